// Round 1
// baseline (883.183 us; speedup 1.0000x reference)
//
#include <hip/hip_runtime.h>

// GCN: h1 = relu(GCNConv(x,W1,b1)); s1 = pool(h1); h2 = relu(GCNConv(h1,W2,b2)); s2 = pool(h2)
// out = [h2 (N*64) | per-graph rows [s1(64) s2(64)] (G*128)]

#define FDIM 64

__global__ void k_count(const int* __restrict__ dst, int E, int* __restrict__ count) {
    int e = blockIdx.x * blockDim.x + threadIdx.x;
    if (e < E) atomicAdd(&count[dst[e]], 1);
}

__global__ void k_dinv(const int* __restrict__ count, int N, float* __restrict__ dinv) {
    int i = blockIdx.x * blockDim.x + threadIdx.x;
    if (i < N) dinv[i] = rsqrtf((float)count[i] + 1.0f);
}

// Single-block exclusive scan of count[0..N) -> row_ptr[0..N], row_ptr[N]=E.
__global__ __launch_bounds__(1024) void k_scan(const int* __restrict__ count, int N, int E,
                                               int* __restrict__ row_ptr) {
    const int T = 1024;
    int t = threadIdx.x;
    int chunk = (N + T - 1) / T;
    int lo = t * chunk;
    int hi = lo + chunk; if (hi > N) hi = N; if (lo > N) lo = N;
    int s = 0;
    for (int i = lo; i < hi; i++) s += count[i];
    __shared__ int sums[T];
    sums[t] = s;
    __syncthreads();
    // Hillis-Steele inclusive scan
    for (int off = 1; off < T; off <<= 1) {
        int v = (t >= off) ? sums[t - off] : 0;
        __syncthreads();
        sums[t] += v;
        __syncthreads();
    }
    int run = sums[t] - s;   // exclusive prefix
    for (int i = lo; i < hi; i++) { row_ptr[i] = run; run += count[i]; }
    if (t == 0) row_ptr[N] = E;
}

__global__ void k_scatter(const int* __restrict__ src, const int* __restrict__ dst, int E,
                          const int* __restrict__ row_ptr, int* __restrict__ fill,
                          int* __restrict__ col) {
    int e = blockIdx.x * blockDim.x + threadIdx.x;
    if (e < E) {
        int d = dst[e];
        int pos = row_ptr[d] + atomicAdd(&fill[d], 1);
        col[pos] = src[e];
    }
}

// G[n,:] = dinv[n] * (X[n,:] @ W)    (64x64 W staged in LDS; 4 rows/block)
__global__ __launch_bounds__(256) void k_gemm_scale(const float* __restrict__ X,
                                                    const float* __restrict__ W,
                                                    const float* __restrict__ dinv, int N,
                                                    float* __restrict__ G) {
    __shared__ float Ws[64][64];
    __shared__ float Xs[4][64];
    int tid = threadIdx.x;
    for (int i = tid; i < 64 * 64; i += 256) Ws[i >> 6][i & 63] = W[i];
    int ty = tid >> 6, c = tid & 63;
    int row = blockIdx.x * 4 + ty;
    if (row < N) Xs[ty][c] = X[(size_t)row * FDIM + c];
    __syncthreads();
    if (row < N) {
        float acc = 0.f;
#pragma unroll
        for (int k = 0; k < 64; k++) acc += Xs[ty][k] * Ws[k][c];
        G[(size_t)row * FDIM + c] = acc * dinv[row];
    }
}

// One wave per node: acc = g[n] + sum over in-edges g[src]; out = relu(dinv[n]*acc + b)
// then pooled via atomics into pool[batch[n]*128 + poolOff + c].
__global__ __launch_bounds__(256) void k_agg(const float* __restrict__ Gm,
                                             const int* __restrict__ row_ptr,
                                             const int* __restrict__ col,
                                             const float* __restrict__ dinv,
                                             const float* __restrict__ bias,
                                             const int* __restrict__ batch, int N,
                                             float* __restrict__ Out,
                                             float* __restrict__ pool, int poolOff) {
    int wave = threadIdx.x >> 6;
    int c = threadIdx.x & 63;
    int n = blockIdx.x * 4 + wave;
    if (n >= N) return;
    float acc = Gm[(size_t)n * FDIM + c];
    int lo = row_ptr[n], hi = row_ptr[n + 1];
    for (int e = lo; e < hi; e++) {
        int s = col[e];
        acc += Gm[(size_t)s * FDIM + c];
    }
    float v = acc * dinv[n] + bias[c];
    v = v > 0.f ? v : 0.f;
    Out[(size_t)n * FDIM + c] = v;
    atomicAdd(&pool[(size_t)batch[n] * 128 + poolOff + c], v);
}

static inline size_t align256(size_t x) { return (x + 255) & ~(size_t)255; }

extern "C" void kernel_launch(void* const* d_in, const int* in_sizes, int n_in,
                              void* d_out, int out_size, void* d_ws, size_t ws_size,
                              hipStream_t stream) {
    const float* x     = (const float*)d_in[0];
    const int*   ei    = (const int*)d_in[1];
    const int*   batch = (const int*)d_in[2];
    const float* W1    = (const float*)d_in[3];
    const float* b1    = (const float*)d_in[4];
    const float* W2    = (const float*)d_in[5];
    const float* b2    = (const float*)d_in[6];

    const int N = in_sizes[0] / FDIM;
    const int E = in_sizes[1] / 2;
    const int* src = ei;
    const int* dst = ei + E;

    char* p = (char*)d_ws;
    int* count   = (int*)p;   p += align256((size_t)N * 4);
    int* fill    = (int*)p;   p += align256((size_t)N * 4);
    int* row_ptr = (int*)p;   p += align256(((size_t)N + 1) * 4);
    int* col     = (int*)p;   p += align256((size_t)E * 4);
    float* dinv  = (float*)p; p += align256((size_t)N * 4);
    float* g     = (float*)p; p += align256((size_t)N * FDIM * 4);
    float* h1    = (float*)p; p += align256((size_t)N * FDIM * 4);

    float* out  = (float*)d_out;
    float* h2   = out;
    float* pool = out + (size_t)N * FDIM;   // [64,128]

    hipMemsetAsync(count, 0, (size_t)N * 4, stream);
    hipMemsetAsync(fill, 0, (size_t)N * 4, stream);
    hipMemsetAsync(pool, 0, (size_t)64 * 128 * 4, stream);

    int eb = (E + 255) / 256;
    int nb = (N + 255) / 256;
    int rb = (N + 3) / 4;

    k_count<<<eb, 256, 0, stream>>>(dst, E, count);
    k_dinv<<<nb, 256, 0, stream>>>(count, N, dinv);
    k_scan<<<1, 1024, 0, stream>>>(count, N, E, row_ptr);
    k_scatter<<<eb, 256, 0, stream>>>(src, dst, E, row_ptr, fill, col);

    // Layer 1
    k_gemm_scale<<<rb, 256, 0, stream>>>(x, W1, dinv, N, g);
    k_agg<<<rb, 256, 0, stream>>>(g, row_ptr, col, dinv, b1, batch, N, h1, pool, 0);

    // Layer 2
    k_gemm_scale<<<rb, 256, 0, stream>>>(h1, W2, dinv, N, g);
    k_agg<<<rb, 256, 0, stream>>>(g, row_ptr, col, dinv, b2, batch, N, h2, pool, 64);
}